// Round 4
// baseline (2745.593 us; speedup 1.0000x reference)
//
#include <hip/hip_runtime.h>
#include <hip/hip_bf16.h>

// LQLinear: out = x @ quantize(weight, basis)^T + bias
// M=8192 tokens, N=4096 out_features, K=4096 in_features.
// Q_T=1 and new_basis is discarded => the LSQ refit does NOT affect output.

#define M_TOK 8192
#define N_OUT 4096
#define K_IN  4096

typedef __attribute__((ext_vector_type(8))) short short8;   // 8 bf16 (4 VGPRs)
typedef __attribute__((ext_vector_type(4))) float floatx4;  // MFMA C/D frag

typedef __attribute__((address_space(1))) const void gvoid_t;
typedef __attribute__((address_space(3))) void lvoid_t;

// round-to-nearest-even fp32 -> bf16 (bit trick; no NaN in this data)
__device__ __forceinline__ ushort f2bf(float f) {
    unsigned u = __float_as_uint(f);
    u += 0x7fffu + ((u >> 16) & 1u);
    return (ushort)(u >> 16);
}

// ---------------- fused prep: x fp32->bf16  +  weight quantize ----------------
#define PREP_XBLK 2048
#define PREP_WBLK 1024

__global__ __launch_bounds__(256) void prep(
        const float4* __restrict__ x,  short8* __restrict__ xb,
        const float4* __restrict__ w,  const float* __restrict__ basis,
        short8* __restrict__ wqo) {
    if (blockIdx.x < PREP_XBLK) {
        const int tid    = blockIdx.x * 256 + threadIdx.x;
        const int stride = PREP_XBLK * 256;
        const int n8     = (M_TOK * K_IN) / 8;
        for (int i = tid; i < n8; i += stride) {
            float4 a = x[2 * i], b = x[2 * i + 1];
            short8 o;
            o[0] = (short)f2bf(a.x); o[1] = (short)f2bf(a.y);
            o[2] = (short)f2bf(a.z); o[3] = (short)f2bf(a.w);
            o[4] = (short)f2bf(b.x); o[5] = (short)f2bf(b.y);
            o[6] = (short)f2bf(b.z); o[7] = (short)f2bf(b.w);
            xb[i] = o;
        }
    } else {
        float b0 = basis[0], b1 = basis[1];
        float l0 = -b0 - b1, l1 = -b0 + b1, l2 = b0 - b1, l3 = b0 + b1;
        float t;
        if (l0 > l1) { t = l0; l0 = l1; l1 = t; }
        if (l2 > l3) { t = l2; l2 = l3; l3 = t; }
        if (l0 > l2) { t = l0; l0 = l2; l2 = t; }
        if (l1 > l3) { t = l1; l1 = l3; l3 = t; }
        if (l1 > l2) { t = l1; l1 = l2; l2 = t; }
        const float t0 = 0.5f * (l0 + l1), t1 = 0.5f * (l1 + l2), t2 = 0.5f * (l2 + l3);
        const int tid    = (blockIdx.x - PREP_XBLK) * 256 + threadIdx.x;
        const int stride = PREP_WBLK * 256;
        const int n8     = (N_OUT * K_IN) / 8;
#define QF(vv) ((vv > t1) ? ((vv > t2) ? l3 : l2) : ((vv > t0) ? l1 : l0))
        for (int i = tid; i < n8; i += stride) {
            float4 a = w[2 * i], b = w[2 * i + 1];
            short8 o;
            o[0] = (short)f2bf(QF(a.x)); o[1] = (short)f2bf(QF(a.y));
            o[2] = (short)f2bf(QF(a.z)); o[3] = (short)f2bf(QF(a.w));
            o[4] = (short)f2bf(QF(b.x)); o[5] = (short)f2bf(QF(b.y));
            o[6] = (short)f2bf(QF(b.z)); o[7] = (short)f2bf(QF(b.w));
            wqo[i] = o;
        }
#undef QF
    }
}

// ---------------- GEMM 256x256, BK=32, 4-phase/2-tiles, 2 blocks/CU ---------
// C[M][N] = A[M][K] * B[N][K]^T + bias. 512 threads = 8 waves (2M x 4N),
// per-wave output 128x64 = acc[8][4] frags of 16x16; BK=32 => each acc frag
// gets exactly one mfma_f32_16x16x32_bf16 per K-tile.
//
// Why BK=32: LDS halves to 64 KiB/block -> 2 blocks/CU. The barrier-pair
// phase structure strictly alternates a block's LDS-read slot and MFMA slot;
// a co-resident second block fills the idle pipe (m114 implicit overlap).
//
// Phases per iteration (2 K-tiles t=2j,2j+1):
//  ph1(buf0): read A0-3+B (8 ds_read) | stage A(t+1)->buf1.A        | 16 MFMA
//  ph2(buf0): read A4-7     (4)       | stage B(t+2)->buf0.B, vmc(2)| 16 MFMA
//  ph3(buf1): read A0-3+B   (8)       | stage A(t+2)->buf0.A        | 16 MFMA
//  ph4(buf1): read A4-7     (4)       | stage B(t+3)->buf1.B, vmc(2)| 16 MFMA
// Write-safety (region dead = fully read before the last barrier):
//  ph1 writes buf1.A : read in ph3/ph4 of iter j-1  -> dead
//  ph2 writes buf0.B : read in ph1                  -> dead
//  ph3 writes buf0.A : read in ph1+ph2              -> dead
//  ph4 writes buf1.B : read in ph3                  -> dead
// vmcnt ledger (1 instr per STAGE, 2 per phase): issue order ...ph4:B(t+1) |
// ph1:A(t+1) | ph2:B(t+2) | ph3:A(t+2) | ph4:B(t+3)... At ph2 post-issue 6
// outstanding -> vmcnt(2) proves {B(t+1),A(t+1)} landed before ph3 reads
// buf1. At ph4 post-issue 6 outstanding -> vmcnt(2) proves {B(t+2),A(t+2)}
// landed before next ph1 reads buf0. Last iter: ph2 uses vmcnt(0).
//
// LDS rows are 32 ushort (64B) = 4 chunks of 16B. Swizzle: phys chunk =
// logical ^ ((row>>1)&3). Frag read (lane=(quad,mrow)): logical chunk = quad;
// any 8 consecutive lanes hit 8 distinct (row-parity, chunk) bank slots ->
// 2 lanes/slot over the wave = free (m136). Staging pre-swizzles the GLOBAL
// source column so the global_load_lds LDS destination stays linear.

#define NIT 64   // iterations; 2 K-tiles each; K = 128 tiles of BK=32

#define BARm() do { asm volatile("" ::: "memory"); \
                    __builtin_amdgcn_s_barrier(); \
                    asm volatile("" ::: "memory"); } while (0)
#define VMC2() asm volatile("s_waitcnt vmcnt(2)" ::: "memory")
#define VMC0() asm volatile("s_waitcnt vmcnt(0)" ::: "memory")

// one global_load_lds per wave: 16 rows x 32 cols (64 lanes x 16B = 1KB)
#define STAGE_A(tt, h)                                                        \
    __builtin_amdgcn_global_load_lds(                                         \
        (gvoid_t*)(ag + (size_t)((h) * 128) * K_IN + (tt) * 32),              \
        (lvoid_t*)(asl + ((tt) & 1) * 8192 + (h) * 4096), 16, 0, 0)
#define STAGE_B(tt, h)                                                        \
    __builtin_amdgcn_global_load_lds(                                         \
        (gvoid_t*)(bg + (size_t)((h) * 128) * K_IN + (tt) * 32),              \
        (lvoid_t*)(bsl + ((tt) & 1) * 8192 + (h) * 4096), 16, 0, 0)

#define READ_AB(PB) do {                                                      \
    const ushort* Ab = As + (PB) * 8192 + aoff;                               \
    const ushort* Bb = Bs + (PB) * 8192 + boff;                               \
    _Pragma("unroll") for (int q = 0; q < 4; ++q) {                           \
        af[q] = *(const short8*)(Ab + q * 512);                               \
        bf[q] = *(const short8*)(Bb + q * 512);                               \
    }                                                                         \
} while (0)

#define READ_A2(PB) do {                                                      \
    const ushort* Ab = As + (PB) * 8192 + aoff + 2048;                        \
    _Pragma("unroll") for (int q = 0; q < 4; ++q)                             \
        af2[q] = *(const short8*)(Ab + q * 512);                              \
} while (0)

#define MFMA16(R0, AF) do {                                                   \
    __builtin_amdgcn_s_setprio(1);                                            \
    _Pragma("unroll") for (int fi = 0; fi < 4; ++fi)                          \
        _Pragma("unroll") for (int nj = 0; nj < 4; ++nj)                      \
            acc[(R0) + fi][nj] = __builtin_amdgcn_mfma_f32_16x16x32_bf16(     \
                AF[fi], bf[nj], acc[(R0) + fi][nj], 0, 0, 0);                 \
    __builtin_amdgcn_s_setprio(0);                                            \
} while (0)

extern "C" __global__ __launch_bounds__(512, 4) void gemm256(
        const ushort* __restrict__ A,   // bf16 [M][K]
        const ushort* __restrict__ B,   // bf16 [N][K]
        const float* __restrict__ bias, // [N]
        float* __restrict__ C) {        // fp32 [M][N]
    extern __shared__ ushort smem[];    // 64 KiB
    ushort* As = smem;                  // [2][256*32]
    ushort* Bs = smem + 16384;          // [2][256*32]

    const int tid  = threadIdx.x;
    const int lane = tid & 63;
    const int wid  = tid >> 6;          // 0..7
    const int wr   = wid >> 2;          // 0..1
    const int wc   = wid & 3;           // 0..3
    const int wm   = wr * 128;          // wave row offset in 256 tile
    const int wn   = wc * 64;           // wave col offset

    // bijective XCD swizzle: 512 blocks, 512 % 8 == 0
    const int bid = blockIdx.x;
    const int swz = (bid & 7) * 64 + (bid >> 3);
    const int bn0 = (swz & 15) * 256;   // N/256 = 16
    const int bm0 = (swz >> 4) * 256;   // M/256 = 32

    // staging: lane covers row (lane>>2), phys chunk (lane&3); source global
    // chunk = (lane&3) ^ swz(row) with swz(row)=((row>>1)&3) = (lane>>3)&3
    const ushort* ag = A + (size_t)(bm0 + wid * 16 + (lane >> 2)) * K_IN
                         + (((lane & 3) ^ ((lane >> 3) & 3)) * 8);
    const ushort* bg = B + (size_t)(bn0 + wid * 16 + (lane >> 2)) * K_IN
                         + (((lane & 3) ^ ((lane >> 3) & 3)) * 8);
    ushort* asl = As + (wid * 16) * 32;  // wave-uniform LDS base
    ushort* bsl = Bs + (wid * 16) * 32;

    // MFMA frag addressing (16x16x32): lane=(quad,mrow), k = quad*8 + j
    // logical chunk = quad; phys = quad ^ ((row>>1)&3) = quad ^ ((mrow>>1)&3)
    const int mrow = lane & 15;
    const int quad = lane >> 4;
    const int cq   = quad ^ ((mrow >> 1) & 3);
    const int aoff = (wm + mrow) * 32 + cq * 8;
    const int boff = (wn + mrow) * 32 + cq * 8;

    floatx4 acc[8][4] = {};
    short8 af[4], af2[4], bf[4];

    // prologue: tile0 fully + tile1 B; vmcnt(2) proves tile0 landed
    STAGE_B(0, 0); STAGE_B(0, 1);
    STAGE_A(0, 0); STAGE_A(0, 1);
    STAGE_B(1, 0); STAGE_B(1, 1);
    VMC2();
    BARm();

#pragma unroll 1
    for (int j = 0; j < NIT; ++j) {
        const int t = 2 * j;
        const bool more = (j + 1 < NIT);
        // ph1: tile t (buf0), frags 0-3
        READ_AB(0);
        STAGE_A(t + 1, 0); STAGE_A(t + 1, 1);
        BARm();
        MFMA16(0, af);
        BARm();
        // ph2: tile t (buf0), frags 4-7
        READ_A2(0);
        if (more) { STAGE_B(t + 2, 0); STAGE_B(t + 2, 1); VMC2(); }
        else      { VMC0(); }
        BARm();
        MFMA16(4, af2);
        BARm();
        // ph3: tile t+1 (buf1), frags 0-3
        READ_AB(1);
        if (more) { STAGE_A(t + 2, 0); STAGE_A(t + 2, 1); }
        BARm();
        MFMA16(0, af);
        BARm();
        // ph4: tile t+1 (buf1), frags 4-7
        READ_A2(1);
        if (more) { STAGE_B(t + 3, 0); STAGE_B(t + 3, 1); VMC2(); }
        BARm();
        MFMA16(4, af2);
        BARm();
    }

    // epilogue: C/D layout col=lane&15, row=(lane>>4)*4+reg
    const int r0 = (lane >> 4) * 4;
    const int cc = lane & 15;
#pragma unroll
    for (int nj = 0; nj < 4; ++nj) {
        const int col = bn0 + wn + nj * 16 + cc;
        const float bj = bias[col];
#pragma unroll
        for (int mi = 0; mi < 8; ++mi) {
#pragma unroll
            for (int r = 0; r < 4; ++r) {
                const int row = bm0 + wm + mi * 16 + r0 + r;
                C[(size_t)row * N_OUT + col] = acc[mi][nj][r] + bj;
            }
        }
    }
}

extern "C" void kernel_launch(void* const* d_in, const int* in_sizes, int n_in,
                              void* d_out, int out_size, void* d_ws, size_t ws_size,
                              hipStream_t stream) {
    const float* x     = (const float*)d_in[0];  // [8192,4096]
    const float* w     = (const float*)d_in[1];  // [4096,4096]
    const float* bias  = (const float*)d_in[2];  // [4096]
    const float* basis = (const float*)d_in[3];  // [2]
    float* out = (float*)d_out;                  // [8192,4096] fp32

    ushort* Xb = (ushort*)d_ws;                      // 8192*4096 bf16 = 67.1 MB
    ushort* Wq = Xb + (size_t)M_TOK * K_IN;          // 4096*4096 bf16 = 33.5 MB

    prep<<<PREP_XBLK + PREP_WBLK, 256, 0, stream>>>(
        (const float4*)x, (short8*)Xb, (const float4*)w, basis, (short8*)Wq);

    (void)hipFuncSetAttribute((const void*)gemm256,
                              hipFuncAttributeMaxDynamicSharedMemorySize, 65536);
    gemm256<<<dim3(512), 512, 65536, stream>>>(Xb, Wq, bias, out);
}